// Round 1
// baseline (120.056 us; speedup 1.0000x reference)
//
#include <hip/hip_runtime.h>
#include <math.h>

// Problem constants (from reference): B=65536, N=128, A=32, T=64
#define N_ATOMS  128
#define A_ALIGN  32
#define T_TRAIN  64

// One cyclic-Jacobi rotation on symmetric 3x3 Am, accumulating into Vm.
// Template indices keep all register-array indexing compile-time (no scratch).
template<int p, int q, int r>
__device__ __forceinline__ void jrot(float Am[3][3], float Vm[3][3])
{
    float apq = Am[p][q];
    float app = Am[p][p];
    float aqq = Am[q][q];
    float tau = (aqq - app) / (2.0f * apq);          // inf/nan if apq==0 -> selected away
    float tt  = 1.0f / (fabsf(tau) + sqrtf(1.0f + tau * tau));
    float t   = copysignf(tt, tau);
    t = (fabsf(apq) > 1e-20f) ? t : 0.0f;
    float c = 1.0f / sqrtf(1.0f + t * t);
    float s = t * c;
    float arp = Am[r][p], arq = Am[r][q];
    float nrp = c * arp - s * arq;
    float nrq = s * arp + c * arq;
    Am[r][p] = nrp; Am[p][r] = nrp;
    Am[r][q] = nrq; Am[q][r] = nrq;
    Am[p][p] = app - t * apq;
    Am[q][q] = aqq + t * apq;
    Am[p][q] = 0.0f; Am[q][p] = 0.0f;
#pragma unroll
    for (int k = 0; k < 3; ++k) {
        float vp = Vm[k][p], vq = Vm[k][q];
        Vm[k][p] = c * vp - s * vq;
        Vm[k][q] = s * vp + c * vq;
    }
}

// K1: one thread per batch element. Gather align atoms, build P, Jacobi-eigen
// of P^T P, construct rotation R = U~ V~^T (det-correct by construction).
// If FUSED, also applies the transform (fallback when ws is too small).
template<bool FUSED>
__global__ __launch_bounds__(256)
void kabsch_rot_kernel(const float* __restrict__ traj,
                       const float* __restrict__ ref_x,
                       const int*   __restrict__ align_idx,
                       const int*   __restrict__ train_idx,
                       float*       __restrict__ rws,   // [12][B] SoA
                       float*       __restrict__ out,
                       int B)
{
    int b = blockIdx.x * blockDim.x + threadIdx.x;
    if (b >= B) return;
    const float* __restrict__ row = traj + (size_t)b * (N_ATOMS * 3);

    // --- accumulate S = sel^T ref, column sums ---
    float S00=0,S01=0,S02=0,S10=0,S11=0,S12=0,S20=0,S21=0,S22=0;
    float xs0=0,xs1=0,xs2=0, rs0=0,rs1=0,rs2=0;
#pragma unroll
    for (int a = 0; a < A_ALIGN; ++a) {
        int ia = align_idx[a];
        float px = row[ia*3+0], py = row[ia*3+1], pz = row[ia*3+2];
        float rx = ref_x[a*3+0], ry = ref_x[a*3+1], rz = ref_x[a*3+2];
        S00 += px*rx; S01 += px*ry; S02 += px*rz;
        S10 += py*rx; S11 += py*ry; S12 += py*rz;
        S20 += pz*rx; S21 += pz*ry; S22 += pz*rz;
        xs0 += px; xs1 += py; xs2 += pz;
        rs0 += rx; rs1 += ry; rs2 += rz;
    }
    const float inv_a = 1.0f / (float)A_ALIGN;
    float c0 = xs0*inv_a, c1 = xs1*inv_a, c2 = xs2*inv_a;
    // P = (sel - xc)^T ref = S - xc (x) colsum(ref)   (colsum(ref) ~ 0, exact anyway)
    float P00 = S00 - c0*rs0, P01 = S01 - c0*rs1, P02 = S02 - c0*rs2;
    float P10 = S10 - c1*rs0, P11 = S11 - c1*rs1, P12 = S12 - c1*rs2;
    float P20 = S20 - c2*rs0, P21 = S21 - c2*rs1, P22 = S22 - c2*rs2;

    // --- A = P^T P, Jacobi eigendecomposition ---
    float Am[3][3], Vm[3][3];
    Am[0][0] = P00*P00 + P10*P10 + P20*P20;
    Am[0][1] = P00*P01 + P10*P11 + P20*P21;
    Am[0][2] = P00*P02 + P10*P12 + P20*P22;
    Am[1][1] = P01*P01 + P11*P11 + P21*P21;
    Am[1][2] = P01*P02 + P11*P12 + P21*P22;
    Am[2][2] = P02*P02 + P12*P12 + P22*P22;
    Am[1][0]=Am[0][1]; Am[2][0]=Am[0][2]; Am[2][1]=Am[1][2];
    Vm[0][0]=1.f; Vm[0][1]=0.f; Vm[0][2]=0.f;
    Vm[1][0]=0.f; Vm[1][1]=1.f; Vm[1][2]=0.f;
    Vm[2][0]=0.f; Vm[2][1]=0.f; Vm[2][2]=1.f;
#pragma unroll
    for (int sw = 0; sw < 6; ++sw) {
        jrot<0,1,2>(Am, Vm);
        jrot<0,2,1>(Am, Vm);
        jrot<1,2,0>(Am, Vm);
    }

    float l0 = Am[0][0], l1 = Am[1][1], l2 = Am[2][2];
    float v0x=Vm[0][0], v0y=Vm[1][0], v0z=Vm[2][0];
    float v1x=Vm[0][1], v1y=Vm[1][1], v1z=Vm[2][1];
    // sort eigenpairs descending (only columns 0,1 matter; v2 rebuilt by cross)
    if (l0 < l1) { float t; t=l0;l0=l1;l1=t;
                   t=v0x;v0x=v1x;v1x=t; t=v0y;v0y=v1y;v1y=t; t=v0z;v0z=v1z;v1z=t; }
    { float v2x=Vm[0][2], v2y=Vm[1][2], v2z=Vm[2][2];
      if (l0 < l2) { float t; t=l0;l0=l2;l2=t;
                     t=v0x;v0x=v2x;v2x=t; t=v0y;v0y=v2y;v2y=t; t=v0z;v0z=v2z;v2z=t; }
      if (l1 < l2) { float t; t=l1;l1=l2;l2=t;
                     t=v1x;v1x=v2x;v2x=t; t=v1y;v1y=v2y;v2y=t; t=v1z;v1z=v2z;v2z=t; }
    }
    // proper V: v2 = v0 x v1
    float v2x = v0y*v1z - v0z*v1y;
    float v2y = v0z*v1x - v0x*v1z;
    float v2z = v0x*v1y - v0y*v1x;
    // u0 = normalize(P v0)
    float w0x = P00*v0x + P01*v0y + P02*v0z;
    float w0y = P10*v0x + P11*v0y + P12*v0z;
    float w0z = P20*v0x + P21*v0y + P22*v0z;
    float i0 = 1.0f / sqrtf(fmaxf(w0x*w0x+w0y*w0y+w0z*w0z, 1e-30f));
    float u0x=w0x*i0, u0y=w0y*i0, u0z=w0z*i0;
    // u1 = normalize(GS(P v1, u0))
    float w1x = P00*v1x + P01*v1y + P02*v1z;
    float w1y = P10*v1x + P11*v1y + P12*v1z;
    float w1z = P20*v1x + P21*v1y + P22*v1z;
    float d01 = u0x*w1x + u0y*w1y + u0z*w1z;
    w1x -= d01*u0x; w1y -= d01*u0y; w1z -= d01*u0z;
    float i1 = 1.0f / sqrtf(fmaxf(w1x*w1x+w1y*w1y+w1z*w1z, 1e-30f));
    float u1x=w1x*i1, u1y=w1y*i1, u1z=w1z*i1;
    // u2 = u0 x u1  (det(U)=+1; absorbs the diag(1,1,sign) correction)
    float u2x = u0y*u1z - u0z*u1y;
    float u2y = u0z*u1x - u0x*u1z;
    float u2z = u0x*u1y - u0y*u1x;
    // R[i][j] = sum_k uk[i] vk[j]
    float R00 = u0x*v0x + u1x*v1x + u2x*v2x;
    float R01 = u0x*v0y + u1x*v1y + u2x*v2y;
    float R02 = u0x*v0z + u1x*v1z + u2x*v2z;
    float R10 = u0y*v0x + u1y*v1x + u2y*v2x;
    float R11 = u0y*v0y + u1y*v1y + u2y*v2y;
    float R12 = u0y*v0z + u1y*v1z + u2y*v2z;
    float R20 = u0z*v0x + u1z*v1x + u2z*v2x;
    float R21 = u0z*v0y + u1z*v1y + u2z*v2y;
    float R22 = u0z*v0z + u1z*v1z + u2z*v2z;

    if (!FUSED) {
        rws[0*(size_t)B+b]=R00; rws[1*(size_t)B+b]=R01; rws[2*(size_t)B+b]=R02;
        rws[3*(size_t)B+b]=R10; rws[4*(size_t)B+b]=R11; rws[5*(size_t)B+b]=R12;
        rws[6*(size_t)B+b]=R20; rws[7*(size_t)B+b]=R21; rws[8*(size_t)B+b]=R22;
        rws[9*(size_t)B+b]=c0; rws[10*(size_t)B+b]=c1; rws[11*(size_t)B+b]=c2;
    } else {
        float* o = out + (size_t)b * (T_TRAIN*3);
#pragma unroll
        for (int t = 0; t < T_TRAIN; ++t) {
            int ti = train_idx[t];
            float x0 = row[ti*3+0]-c0, x1 = row[ti*3+1]-c1, x2 = row[ti*3+2]-c2;
            o[t*3+0] = x0*R00 + x1*R10 + x2*R20;
            o[t*3+1] = x0*R01 + x1*R11 + x2*R21;
            o[t*3+2] = x0*R02 + x1*R12 + x2*R22;
        }
    }
}

// K2: one wave per batch element (lane = train slot). All 64 lanes read the
// same 1536B traj row -> ~12 L1 lines per instruction; R/xc via wave-uniform
// (scalar) loads; near-coalesced output stores.
__global__ __launch_bounds__(256)
void apply_kernel(const float* __restrict__ traj,
                  const int*   __restrict__ train_idx,
                  const float* __restrict__ rws,
                  float*       __restrict__ out,
                  int B)
{
    int tid = blockIdx.x * blockDim.x + threadIdx.x;
    int b = tid >> 6;
    int t = tid & 63;
    if (b >= B) return;
    int bu = __builtin_amdgcn_readfirstlane(b);   // b is wave-uniform

    float R00 = rws[0*(size_t)B+bu], R01 = rws[1*(size_t)B+bu], R02 = rws[2*(size_t)B+bu];
    float R10 = rws[3*(size_t)B+bu], R11 = rws[4*(size_t)B+bu], R12 = rws[5*(size_t)B+bu];
    float R20 = rws[6*(size_t)B+bu], R21 = rws[7*(size_t)B+bu], R22 = rws[8*(size_t)B+bu];
    float c0  = rws[9*(size_t)B+bu], c1  = rws[10*(size_t)B+bu], c2 = rws[11*(size_t)B+bu];

    int ti = train_idx[t];
    const float* p = traj + ((size_t)b * N_ATOMS + ti) * 3;
    float x0 = p[0]-c0, x1 = p[1]-c1, x2 = p[2]-c2;
    float y0 = x0*R00 + x1*R10 + x2*R20;
    float y1 = x0*R01 + x1*R11 + x2*R21;
    float y2 = x0*R02 + x1*R12 + x2*R22;
    float* o = out + (size_t)b*(T_TRAIN*3) + t*3;
    o[0]=y0; o[1]=y1; o[2]=y2;
}

extern "C" void kernel_launch(void* const* d_in, const int* in_sizes, int n_in,
                              void* d_out, int out_size, void* d_ws, size_t ws_size,
                              hipStream_t stream)
{
    const float* traj      = (const float*)d_in[0];
    const float* ref_x     = (const float*)d_in[1];
    const int*   align_idx = (const int*)d_in[2];
    const int*   train_idx = (const int*)d_in[3];
    float* out = (float*)d_out;
    int B = in_sizes[0] / (N_ATOMS * 3);

    size_t need = (size_t)12 * (size_t)B * sizeof(float);
    if (ws_size >= need) {
        float* rws = (float*)d_ws;
        kabsch_rot_kernel<false><<<dim3((B + 255) / 256), dim3(256), 0, stream>>>(
            traj, ref_x, align_idx, train_idx, rws, out, B);
        int total = B * 64;
        apply_kernel<<<dim3((total + 255) / 256), dim3(256), 0, stream>>>(
            traj, train_idx, rws, out, B);
    } else {
        // ws too small: fused fallback (slower gather pattern, still correct)
        kabsch_rot_kernel<true><<<dim3((B + 255) / 256), dim3(256), 0, stream>>>(
            traj, ref_x, align_idx, train_idx, nullptr, out, B);
    }
}

// Round 2
// 79.854 us; speedup vs baseline: 1.5034x; 1.5034x over previous
//
#include <hip/hip_runtime.h>
#include <math.h>

// Problem constants (from reference): B=65536, N=128, A=32, T=64
#define N_ATOMS  128
#define A_ALIGN  32
#define T_TRAIN  64
#define BPB      8            // batch rows per block
#define ROWF     (N_ATOMS*3)  // 384 floats per row
#define RPAD     388          // padded LDS row stride (floats): 388%32=4 -> row readers on distinct banks

// One cyclic-Jacobi rotation on symmetric 3x3 Am, accumulating into Vm.
// Template indices keep all register-array indexing compile-time (no scratch).
template<int p, int q, int r>
__device__ __forceinline__ void jrot(float Am[3][3], float Vm[3][3])
{
    float apq = Am[p][q];
    float app = Am[p][p];
    float aqq = Am[q][q];
    float tau = (aqq - app) / (2.0f * apq);
    float tt  = 1.0f / (fabsf(tau) + sqrtf(1.0f + tau * tau));
    float t   = copysignf(tt, tau);
    t = (fabsf(apq) > 1e-20f) ? t : 0.0f;
    float c = 1.0f / sqrtf(1.0f + t * t);
    float s = t * c;
    float arp = Am[r][p], arq = Am[r][q];
    float nrp = c * arp - s * arq;
    float nrq = s * arp + c * arq;
    Am[r][p] = nrp; Am[p][r] = nrp;
    Am[r][q] = nrq; Am[q][r] = nrq;
    Am[p][p] = app - t * apq;
    Am[q][q] = aqq + t * apq;
    Am[p][q] = 0.0f; Am[q][p] = 0.0f;
#pragma unroll
    for (int k = 0; k < 3; ++k) {
        float vp = Vm[k][p], vq = Vm[k][q];
        Vm[k][p] = c * vp - s * vq;
        Vm[k][q] = s * vp + c * vq;
    }
}

// Fused: stage 8 rows -> LDS (coalesced float4), 8 lanes do Kabsch, all
// threads apply the rotation to train atoms and store.
__global__ __launch_bounds__(256, 4)
void kabsch_fused_kernel(const float* __restrict__ traj,
                         const float* __restrict__ ref_x,
                         const int*   __restrict__ align_idx,
                         const int*   __restrict__ train_idx,
                         float*       __restrict__ out)
{
    __shared__ float rowbuf[BPB * RPAD];
    __shared__ float Rc[BPB][12];

    const int tid = threadIdx.x;
    const size_t bbase = (size_t)blockIdx.x * BPB;

    // ---- stage: 8 rows = 3072 floats = 768 float4, 3 per thread, coalesced ----
    const float4* __restrict__ gsrc =
        (const float4*)(traj + bbase * ROWF);
#pragma unroll
    for (int k = 0; k < 3; ++k) {
        int f4  = tid + k * 256;        // float4 index within the 8-row chunk
        float4 v = gsrc[f4];
        int row = f4 / 96;              // 96 float4 per row
        int wi  = (f4 - row * 96) * 4;  // float offset within row
        // row*RPAD*4 = 1552B, 1552%16==0 and wi*4%16==0 -> 16B-aligned LDS store
        *(float4*)&rowbuf[row * RPAD + wi] = v;
    }
    __syncthreads();

    // ---- Kabsch: lanes 0..7 of wave 0, one row each ----
    if (tid < BPB) {
        const float* __restrict__ row = &rowbuf[tid * RPAD];

        float S00=0,S01=0,S02=0,S10=0,S11=0,S12=0,S20=0,S21=0,S22=0;
        float xs0=0,xs1=0,xs2=0, rs0=0,rs1=0,rs2=0;
#pragma unroll
        for (int a = 0; a < A_ALIGN; ++a) {
            int ia = align_idx[a];                       // uniform -> scalar load
            float px = row[ia*3+0], py = row[ia*3+1], pz = row[ia*3+2];
            float rx = ref_x[a*3+0], ry = ref_x[a*3+1], rz = ref_x[a*3+2];
            S00 += px*rx; S01 += px*ry; S02 += px*rz;
            S10 += py*rx; S11 += py*ry; S12 += py*rz;
            S20 += pz*rx; S21 += pz*ry; S22 += pz*rz;
            xs0 += px; xs1 += py; xs2 += pz;
            rs0 += rx; rs1 += ry; rs2 += rz;
        }
        const float inv_a = 1.0f / (float)A_ALIGN;
        float c0 = xs0*inv_a, c1 = xs1*inv_a, c2 = xs2*inv_a;
        float P00 = S00 - c0*rs0, P01 = S01 - c0*rs1, P02 = S02 - c0*rs2;
        float P10 = S10 - c1*rs0, P11 = S11 - c1*rs1, P12 = S12 - c1*rs2;
        float P20 = S20 - c2*rs0, P21 = S21 - c2*rs1, P22 = S22 - c2*rs2;

        float Am[3][3], Vm[3][3];
        Am[0][0] = P00*P00 + P10*P10 + P20*P20;
        Am[0][1] = P00*P01 + P10*P11 + P20*P21;
        Am[0][2] = P00*P02 + P10*P12 + P20*P22;
        Am[1][1] = P01*P01 + P11*P11 + P21*P21;
        Am[1][2] = P01*P02 + P11*P12 + P21*P22;
        Am[2][2] = P02*P02 + P12*P12 + P22*P22;
        Am[1][0]=Am[0][1]; Am[2][0]=Am[0][2]; Am[2][1]=Am[1][2];
        Vm[0][0]=1.f; Vm[0][1]=0.f; Vm[0][2]=0.f;
        Vm[1][0]=0.f; Vm[1][1]=1.f; Vm[1][2]=0.f;
        Vm[2][0]=0.f; Vm[2][1]=0.f; Vm[2][2]=1.f;
#pragma unroll
        for (int sw = 0; sw < 6; ++sw) {
            jrot<0,1,2>(Am, Vm);
            jrot<0,2,1>(Am, Vm);
            jrot<1,2,0>(Am, Vm);
        }

        float l0 = Am[0][0], l1 = Am[1][1], l2 = Am[2][2];
        float v0x=Vm[0][0], v0y=Vm[1][0], v0z=Vm[2][0];
        float v1x=Vm[0][1], v1y=Vm[1][1], v1z=Vm[2][1];
        if (l0 < l1) { float t; t=l0;l0=l1;l1=t;
                       t=v0x;v0x=v1x;v1x=t; t=v0y;v0y=v1y;v1y=t; t=v0z;v0z=v1z;v1z=t; }
        { float v2x=Vm[0][2], v2y=Vm[1][2], v2z=Vm[2][2];
          if (l0 < l2) { float t; t=l0;l0=l2;l2=t;
                         t=v0x;v0x=v2x;v2x=t; t=v0y;v0y=v2y;v2y=t; t=v0z;v0z=v2z;v2z=t; }
          if (l1 < l2) { float t; t=l1;l1=l2;l2=t;
                         t=v1x;v1x=v2x;v2x=t; t=v1y;v1y=v2y;v2y=t; t=v1z;v1z=v2z;v2z=t; }
        }
        float v2x = v0y*v1z - v0z*v1y;
        float v2y = v0z*v1x - v0x*v1z;
        float v2z = v0x*v1y - v0y*v1x;
        float w0x = P00*v0x + P01*v0y + P02*v0z;
        float w0y = P10*v0x + P11*v0y + P12*v0z;
        float w0z = P20*v0x + P21*v0y + P22*v0z;
        float i0 = 1.0f / sqrtf(fmaxf(w0x*w0x+w0y*w0y+w0z*w0z, 1e-30f));
        float u0x=w0x*i0, u0y=w0y*i0, u0z=w0z*i0;
        float w1x = P00*v1x + P01*v1y + P02*v1z;
        float w1y = P10*v1x + P11*v1y + P12*v1z;
        float w1z = P20*v1x + P21*v1y + P22*v1z;
        float d01 = u0x*w1x + u0y*w1y + u0z*w1z;
        w1x -= d01*u0x; w1y -= d01*u0y; w1z -= d01*u0z;
        float i1 = 1.0f / sqrtf(fmaxf(w1x*w1x+w1y*w1y+w1z*w1z, 1e-30f));
        float u1x=w1x*i1, u1y=w1y*i1, u1z=w1z*i1;
        float u2x = u0y*u1z - u0z*u1y;
        float u2y = u0z*u1x - u0x*u1z;
        float u2z = u0x*u1y - u0y*u1x;

        Rc[tid][0] = u0x*v0x + u1x*v1x + u2x*v2x;
        Rc[tid][1] = u0x*v0y + u1x*v1y + u2x*v2y;
        Rc[tid][2] = u0x*v0z + u1x*v1z + u2x*v2z;
        Rc[tid][3] = u0y*v0x + u1y*v1x + u2y*v2x;
        Rc[tid][4] = u0y*v0y + u1y*v1y + u2y*v2y;
        Rc[tid][5] = u0y*v0z + u1y*v1z + u2y*v2z;
        Rc[tid][6] = u0z*v0x + u1z*v1x + u2z*v2x;
        Rc[tid][7] = u0z*v0y + u1z*v1y + u2z*v2y;
        Rc[tid][8] = u0z*v0z + u1z*v1z + u2z*v2z;
        Rc[tid][9]  = c0;
        Rc[tid][10] = c1;
        Rc[tid][11] = c2;
    }
    __syncthreads();

    // ---- transform: 8 rows x 64 train atoms = 512, 2 per thread.
    // Wave w handles row w+4k -> Rc reads are wave-uniform broadcasts.
#pragma unroll
    for (int k = 0; k < 2; ++k) {
        int a = tid + k * 256;
        int r = a >> 6;
        int t = a & 63;
        int ti = train_idx[t];                    // same line across wave
        const float* __restrict__ rb = &rowbuf[r * RPAD];
        float c0 = Rc[r][9], c1 = Rc[r][10], c2 = Rc[r][11];
        float x0 = rb[ti*3+0]-c0, x1 = rb[ti*3+1]-c1, x2 = rb[ti*3+2]-c2;
        float y0 = x0*Rc[r][0] + x1*Rc[r][3] + x2*Rc[r][6];
        float y1 = x0*Rc[r][1] + x1*Rc[r][4] + x2*Rc[r][7];
        float y2 = x0*Rc[r][2] + x1*Rc[r][5] + x2*Rc[r][8];
        float* o = out + ((bbase + r) * T_TRAIN + t) * 3;
        o[0]=y0; o[1]=y1; o[2]=y2;
    }
}

extern "C" void kernel_launch(void* const* d_in, const int* in_sizes, int n_in,
                              void* d_out, int out_size, void* d_ws, size_t ws_size,
                              hipStream_t stream)
{
    const float* traj      = (const float*)d_in[0];
    const float* ref_x     = (const float*)d_in[1];
    const int*   align_idx = (const int*)d_in[2];
    const int*   train_idx = (const int*)d_in[3];
    float* out = (float*)d_out;
    int B = in_sizes[0] / (N_ATOMS * 3);

    kabsch_fused_kernel<<<dim3(B / BPB), dim3(256), 0, stream>>>(
        traj, ref_x, align_idx, train_idx, out);
}

// Round 3
// 59.455 us; speedup vs baseline: 2.0193x; 1.3431x over previous
//
#include <hip/hip_runtime.h>
#include <math.h>

// Problem constants (from reference): B=65536, N=128, A=32, T=64
#define N_ATOMS  128
#define A_ALIGN  32
#define T_TRAIN  64
#define BPB      32           // batch rows per block
#define ROWF     (N_ATOMS*3)  // 384 floats per row
#define RPAD     388          // padded LDS row stride (floats); 1552B, 16B-aligned

// One cyclic-Jacobi rotation on symmetric 3x3 Am, accumulating into Vm.
template<int p, int q, int r>
__device__ __forceinline__ void jrot(float Am[3][3], float Vm[3][3])
{
    float apq = Am[p][q];
    float app = Am[p][p];
    float aqq = Am[q][q];
    float tau = (aqq - app) / (2.0f * apq);
    float tt  = 1.0f / (fabsf(tau) + sqrtf(1.0f + tau * tau));
    float t   = copysignf(tt, tau);
    t = (fabsf(apq) > 1e-20f) ? t : 0.0f;
    float c = 1.0f / sqrtf(1.0f + t * t);
    float s = t * c;
    float arp = Am[r][p], arq = Am[r][q];
    float nrp = c * arp - s * arq;
    float nrq = s * arp + c * arq;
    Am[r][p] = nrp; Am[p][r] = nrp;
    Am[r][q] = nrq; Am[q][r] = nrq;
    Am[p][p] = app - t * apq;
    Am[q][q] = aqq + t * apq;
    Am[p][q] = 0.0f; Am[q][p] = 0.0f;
#pragma unroll
    for (int k = 0; k < 3; ++k) {
        float vp = Vm[k][p], vq = Vm[k][q];
        Vm[k][p] = c * vp - s * vq;
        Vm[k][q] = s * vp + c * vq;
    }
}

__global__ __launch_bounds__(256)
void kabsch_fused_kernel(const float* __restrict__ traj,
                         const float* __restrict__ ref_x,
                         const int*   __restrict__ align_idx,
                         const int*   __restrict__ train_idx,
                         float*       __restrict__ out,
                         int B)
{
    __shared__ float rowbuf[BPB * RPAD];     // 49664 B
    __shared__ float Rc[BPB][12];            // 1536 B
    __shared__ float refb[A_ALIGN * 3];      // 384 B
    __shared__ int   idxa[A_ALIGN];          // align indices
    __shared__ int   idxt[T_TRAIN];          // train indices

    const int tid = threadIdx.x;
    const long long bbase = (long long)blockIdx.x * BPB;

    // ---- tiny tables ----
    if (tid < A_ALIGN)          idxa[tid] = align_idx[tid];
    if (tid < T_TRAIN)          idxt[tid] = train_idx[tid];
    if (tid < A_ALIGN * 3)      refb[tid] = ref_x[tid];

    // ---- stage: 32 rows = 12288 floats = 3072 float4, 12/thread, coalesced ----
    const float4* __restrict__ gsrc = (const float4*)(traj + bbase * ROWF);
    const long long f4max = ((long long)B * ROWF) / 4 - (bbase * ROWF) / 4;
#pragma unroll
    for (int k = 0; k < 12; ++k) {
        int f4 = tid + k * 256;
        if (f4 < f4max) {
            float4 v = gsrc[f4];
            int row = f4 / 96;              // 96 float4 per row
            int wi  = (f4 - row * 96) * 4;
            *(float4*)&rowbuf[row * RPAD + wi] = v;
        }
    }
    __syncthreads();

    // ---- Kabsch: 32 lanes of wave (blockIdx&3), one row per lane ----
    // Spreads the serial chain across SIMDs block-to-block.
    const int kw = blockIdx.x & 3;
    if ((tid >> 6) == kw && (tid & 63) < 32 && (bbase + (tid & 63)) < B) {
        const int l = tid & 63;              // row within block
        const float* __restrict__ row = &rowbuf[l * RPAD];

        float S00=0,S01=0,S02=0,S10=0,S11=0,S12=0,S20=0,S21=0,S22=0;
        float xs0=0,xs1=0,xs2=0, rs0=0,rs1=0,rs2=0;
#pragma unroll
        for (int a = 0; a < A_ALIGN; ++a) {
            int ap = (a + l) & (A_ALIGN - 1);    // rotated order: bank-spread + valid (sum is commutative)
            int ia = idxa[ap];
            float px = row[ia*3+0], py = row[ia*3+1], pz = row[ia*3+2];
            float rx = refb[ap*3+0], ry = refb[ap*3+1], rz = refb[ap*3+2];
            S00 += px*rx; S01 += px*ry; S02 += px*rz;
            S10 += py*rx; S11 += py*ry; S12 += py*rz;
            S20 += pz*rx; S21 += pz*ry; S22 += pz*rz;
            xs0 += px; xs1 += py; xs2 += pz;
            rs0 += rx; rs1 += ry; rs2 += rz;
        }
        const float inv_a = 1.0f / (float)A_ALIGN;
        float c0 = xs0*inv_a, c1 = xs1*inv_a, c2 = xs2*inv_a;
        float P00 = S00 - c0*rs0, P01 = S01 - c0*rs1, P02 = S02 - c0*rs2;
        float P10 = S10 - c1*rs0, P11 = S11 - c1*rs1, P12 = S12 - c1*rs2;
        float P20 = S20 - c2*rs0, P21 = S21 - c2*rs1, P22 = S22 - c2*rs2;

        float Am[3][3], Vm[3][3];
        Am[0][0] = P00*P00 + P10*P10 + P20*P20;
        Am[0][1] = P00*P01 + P10*P11 + P20*P21;
        Am[0][2] = P00*P02 + P10*P12 + P20*P22;
        Am[1][1] = P01*P01 + P11*P11 + P21*P21;
        Am[1][2] = P01*P02 + P11*P12 + P21*P22;
        Am[2][2] = P02*P02 + P12*P12 + P22*P22;
        Am[1][0]=Am[0][1]; Am[2][0]=Am[0][2]; Am[2][1]=Am[1][2];
        Vm[0][0]=1.f; Vm[0][1]=0.f; Vm[0][2]=0.f;
        Vm[1][0]=0.f; Vm[1][1]=1.f; Vm[1][2]=0.f;
        Vm[2][0]=0.f; Vm[2][1]=0.f; Vm[2][2]=1.f;
#pragma unroll
        for (int sw = 0; sw < 6; ++sw) {
            jrot<0,1,2>(Am, Vm);
            jrot<0,2,1>(Am, Vm);
            jrot<1,2,0>(Am, Vm);
        }

        float l0 = Am[0][0], l1 = Am[1][1], l2 = Am[2][2];
        float v0x=Vm[0][0], v0y=Vm[1][0], v0z=Vm[2][0];
        float v1x=Vm[0][1], v1y=Vm[1][1], v1z=Vm[2][1];
        if (l0 < l1) { float t; t=l0;l0=l1;l1=t;
                       t=v0x;v0x=v1x;v1x=t; t=v0y;v0y=v1y;v1y=t; t=v0z;v0z=v1z;v1z=t; }
        { float v2x=Vm[0][2], v2y=Vm[1][2], v2z=Vm[2][2];
          if (l0 < l2) { float t; t=l0;l0=l2;l2=t;
                         t=v0x;v0x=v2x;v2x=t; t=v0y;v0y=v2y;v2y=t; t=v0z;v0z=v2z;v2z=t; }
          if (l1 < l2) { float t; t=l1;l1=l2;l2=t;
                         t=v1x;v1x=v2x;v2x=t; t=v1y;v1y=v2y;v2y=t; t=v1z;v1z=v2z;v2z=t; }
        }
        float v2x = v0y*v1z - v0z*v1y;
        float v2y = v0z*v1x - v0x*v1z;
        float v2z = v0x*v1y - v0y*v1x;
        float w0x = P00*v0x + P01*v0y + P02*v0z;
        float w0y = P10*v0x + P11*v0y + P12*v0z;
        float w0z = P20*v0x + P21*v0y + P22*v0z;
        float i0 = 1.0f / sqrtf(fmaxf(w0x*w0x+w0y*w0y+w0z*w0z, 1e-30f));
        float u0x=w0x*i0, u0y=w0y*i0, u0z=w0z*i0;
        float w1x = P00*v1x + P01*v1y + P02*v1z;
        float w1y = P10*v1x + P11*v1y + P12*v1z;
        float w1z = P20*v1x + P21*v1y + P22*v1z;
        float d01 = u0x*w1x + u0y*w1y + u0z*w1z;
        w1x -= d01*u0x; w1y -= d01*u0y; w1z -= d01*u0z;
        float i1 = 1.0f / sqrtf(fmaxf(w1x*w1x+w1y*w1y+w1z*w1z, 1e-30f));
        float u1x=w1x*i1, u1y=w1y*i1, u1z=w1z*i1;
        float u2x = u0y*u1z - u0z*u1y;
        float u2y = u0z*u1x - u0x*u1z;
        float u2z = u0x*u1y - u0y*u1x;

        Rc[l][0] = u0x*v0x + u1x*v1x + u2x*v2x;
        Rc[l][1] = u0x*v0y + u1x*v1y + u2x*v2y;
        Rc[l][2] = u0x*v0z + u1x*v1z + u2x*v2z;
        Rc[l][3] = u0y*v0x + u1y*v1x + u2y*v2x;
        Rc[l][4] = u0y*v0y + u1y*v1y + u2y*v2y;
        Rc[l][5] = u0y*v0z + u1y*v1z + u2y*v2z;
        Rc[l][6] = u0z*v0x + u1z*v1x + u2z*v2x;
        Rc[l][7] = u0z*v0y + u1z*v1y + u2z*v2y;
        Rc[l][8] = u0z*v0z + u1z*v1z + u2z*v2z;
        Rc[l][9]  = c0;
        Rc[l][10] = c1;
        Rc[l][11] = c2;
    }
    __syncthreads();

    // ---- transform: 32 rows x 64 train atoms = 2048, 8 per thread ----
#pragma unroll
    for (int k = 0; k < 8; ++k) {
        int a = tid + k * 256;
        int r = a >> 6;
        int t = a & 63;
        if (bbase + r >= B) break;
        int ti = idxt[t];
        const float* __restrict__ rb = &rowbuf[r * RPAD];
        float c0 = Rc[r][9], c1 = Rc[r][10], c2 = Rc[r][11];
        float x0 = rb[ti*3+0]-c0, x1 = rb[ti*3+1]-c1, x2 = rb[ti*3+2]-c2;
        float y0 = x0*Rc[r][0] + x1*Rc[r][3] + x2*Rc[r][6];
        float y1 = x0*Rc[r][1] + x1*Rc[r][4] + x2*Rc[r][7];
        float y2 = x0*Rc[r][2] + x1*Rc[r][5] + x2*Rc[r][8];
        float* o = out + ((bbase + r) * T_TRAIN + t) * 3;
        o[0]=y0; o[1]=y1; o[2]=y2;
    }
}

extern "C" void kernel_launch(void* const* d_in, const int* in_sizes, int n_in,
                              void* d_out, int out_size, void* d_ws, size_t ws_size,
                              hipStream_t stream)
{
    const float* traj      = (const float*)d_in[0];
    const float* ref_x     = (const float*)d_in[1];
    const int*   align_idx = (const int*)d_in[2];
    const int*   train_idx = (const int*)d_in[3];
    float* out = (float*)d_out;
    int B = in_sizes[0] / (N_ATOMS * 3);

    int nblk = (B + BPB - 1) / BPB;
    kabsch_fused_kernel<<<dim3(nblk), dim3(256), 0, stream>>>(
        traj, ref_x, align_idx, train_idx, out, B);
}